// Round 10
// baseline (141.916 us; speedup 1.0000x reference)
//
#include <hip/hip_runtime.h>

#define BB 4
#define NN 512
#define DD 16
#define EE 16
#define HH 128

typedef float f32x4 __attribute__((ext_vector_type(4)));

#define LD4(p) (*(const float4*)(p))

// Kernel 1: proj_j[b,j,h] = sum_d node_feature[b,j,d] * W_edge[D+d][h]
__global__ void proj_j_kernel(const float* __restrict__ nf,
                              const float* __restrict__ W_edge,
                              float* __restrict__ pj) {
    int idx = blockIdx.x * 256 + threadIdx.x;
    if (idx >= BB * NN * HH) return;
    int h  = idx & (HH - 1);
    int bj = idx >> 7;
    const float* row = nf + bj * DD;
    float acc = 0.f;
#pragma unroll
    for (int d = 0; d < DD; ++d)
        acc = fmaf(row[d], W_edge[(DD + d) * HH + h], acc);
    pj[idx] = acc;
}

// Kernel 2: one block per (b,i). 128 threads = 2 waves.
// Identical to round 9 EXCEPT the edge_out store: inline-asm
// global_store_dwordx4 with sc0 sc1 nt (system-scope L2-BYPASS streaming)
// instead of __builtin_nontemporal_store (nt-only: L2 write-back w/ early evict).
template <bool USE_WS>
__global__ __launch_bounds__(128, 2)
void fused_kernel(const float* __restrict__ node_feature,
                  const float* __restrict__ adjacency,
                  const float* __restrict__ edge_feature,
                  const float* __restrict__ W_edge,
                  const float* __restrict__ b_edge,
                  const float* __restrict__ W_feat,
                  const float* __restrict__ b_feat,
                  const float* __restrict__ pj,
                  float* __restrict__ out_end,
                  float* __restrict__ out_edge) {
    const int bi = blockIdx.x;           // b*N + i
    const int b  = bi >> 9;
    const int t  = threadIdx.x;          // 0..127
    const int hq = t & 31;
    const int h0 = hq * 4;
    const bool hi = (t & 32) != 0;       // odd row within the wave's pair
    const int jw = __builtin_amdgcn_readfirstlane(2 * (t >> 6)); // 0 or 2 (SGPR)

    // We columns (rows 2D..2D+E-1 of W_edge)
    float4 we[EE];
#pragma unroll
    for (int e = 0; e < EE; ++e)
        we[e] = LD4(W_edge + (2 * DD + e) * HH + h0);

    // pi = b_edge + nf_i @ Wi   (own row i)
    float4 pi = LD4(b_edge + h0);
    {
        const float* nfi = node_feature + bi * DD;
#pragma unroll
        for (int d4 = 0; d4 < DD; d4 += 4) {
            float4 v = LD4(nfi + d4);
            float nd[4] = {v.x, v.y, v.z, v.w};
#pragma unroll
            for (int q = 0; q < 4; ++q) {
                float4 wi = LD4(W_edge + (d4 + q) * HH + h0);
                pi.x = fmaf(nd[q], wi.x, pi.x);
                pi.y = fmaf(nd[q], wi.y, pi.y);
                pi.z = fmaf(nd[q], wi.z, pi.z);
                pi.w = fmaf(nd[q], wi.w, pi.w);
            }
        }
    }

    const float* efb  = edge_feature + (size_t)bi * NN * EE;
    const float* adjr = adjacency + (size_t)bi * NN;
    const float* pjb  = pj + (b * NN) * HH;
    float*       eob  = out_edge + (size_t)bi * NN * HH;

    float4 msg = make_float4(0.f, 0.f, 0.f, 0.f);

    // ---- prefetch iteration 0 ----
    int j0 = jw;                                   // uniform row base
    float sefA0[EE], sefA1[EE];
#pragma unroll
    for (int e = 0; e < EE; ++e) {
        sefA0[e] = efb[j0 * EE + e];               // uniform addr -> s_load
        sefA1[e] = efb[(j0 + 1) * EE + e];
    }
    float adjA0 = adjr[j0];
    float adjA1 = adjr[j0 + 1];
    int   jsel  = j0 + (hi ? 1 : 0);               // per-lane row
    float4 pjA  = make_float4(0.f, 0.f, 0.f, 0.f);
    if constexpr (USE_WS) pjA = LD4(pjb + jsel * HH + h0);

    for (int it = 0; it < NN / 4; ++it) {
        const int itn = (it + 1 < NN / 4) ? it + 1 : it;
        const int j0n = 4 * itn + jw;              // uniform next base
        const int jseln = j0n + (hi ? 1 : 0);

        // ---- prefetch next iteration (scalar ef/adj, vector pj) ----
        float sefB0[EE], sefB1[EE];
#pragma unroll
        for (int e = 0; e < EE; ++e) {
            sefB0[e] = efb[j0n * EE + e];
            sefB1[e] = efb[(j0n + 1) * EE + e];
        }
        float adjB0 = adjr[j0n];
        float adjB1 = adjr[j0n + 1];
        float4 pjB  = make_float4(0.f, 0.f, 0.f, 0.f);
        if constexpr (USE_WS) pjB = LD4(pjb + jseln * HH + h0);

        // ---- compute current ----
        float4 acc;
        if constexpr (USE_WS) {
            acc.x = pi.x + pjA.x;
            acc.y = pi.y + pjA.y;
            acc.z = pi.z + pjA.z;
            acc.w = pi.w + pjA.w;
        } else {
            acc = pi;
        }

        float ef_[EE];
#pragma unroll
        for (int e = 0; e < EE; ++e)
            ef_[e] = hi ? sefA1[e] : sefA0[e];     // 1 cndmask each

#pragma unroll
        for (int e = 0; e < EE; ++e) {
            acc.x = fmaf(ef_[e], we[e].x, acc.x);
            acc.y = fmaf(ef_[e], we[e].y, acc.y);
            acc.z = fmaf(ef_[e], we[e].z, acc.z);
            acc.w = fmaf(ef_[e], we[e].w, acc.w);
        }
        acc.x = fmaxf(acc.x, 0.f);
        acc.y = fmaxf(acc.y, 0.f);
        acc.z = fmaxf(acc.z, 0.f);
        acc.w = fmaxf(acc.w, 0.f);

        // L2-BYPASS streaming store: system-scope + non-temporal
        {
            f32x4 accv = {acc.x, acc.y, acc.z, acc.w};
            float* dst = eob + (size_t)jsel * HH + h0;
            asm volatile("global_store_dwordx4 %0, %1, off sc0 sc1 nt"
                         :: "v"(dst), "v"(accv) : "memory");
        }

        float adjv = hi ? adjA1 : adjA0;
        msg.x = fmaf(adjv, acc.x, msg.x);
        msg.y = fmaf(adjv, acc.y, msg.y);
        msg.z = fmaf(adjv, acc.z, msg.z);
        msg.w = fmaf(adjv, acc.w, msg.w);

        // rotate prefetch buffers
#pragma unroll
        for (int e = 0; e < EE; ++e) { sefA0[e] = sefB0[e]; sefA1[e] = sefB1[e]; }
        adjA0 = adjB0; adjA1 = adjB1; pjA = pjB;
        jsel = jseln;
    }

    // Reduce message across the 4 row-phases, then ending = relu([msg,nf]@W_feat + b_feat)
    __shared__ float msgred[4][HH];
    *(float4*)&msgred[t >> 5][h0] = msg;
    __syncthreads();

    if (t < 32) {
        float4 acc = LD4(b_feat + h0);
#pragma unroll 4
        for (int k = 0; k < HH; ++k) {
            float m = msgred[0][k] + msgred[1][k] + msgred[2][k] + msgred[3][k];
            float4 w = LD4(W_feat + k * HH + h0);
            acc.x = fmaf(m, w.x, acc.x);
            acc.y = fmaf(m, w.y, acc.y);
            acc.z = fmaf(m, w.z, acc.z);
            acc.w = fmaf(m, w.w, acc.w);
        }
        const float* nfi = node_feature + bi * DD;
#pragma unroll
        for (int d = 0; d < DD; ++d) {
            float m = nfi[d];
            float4 w = LD4(W_feat + (HH + d) * HH + h0);
            acc.x = fmaf(m, w.x, acc.x);
            acc.y = fmaf(m, w.y, acc.y);
            acc.z = fmaf(m, w.z, acc.z);
            acc.w = fmaf(m, w.w, acc.w);
        }
        acc.x = fmaxf(acc.x, 0.f);
        acc.y = fmaxf(acc.y, 0.f);
        acc.z = fmaxf(acc.z, 0.f);
        acc.w = fmaxf(acc.w, 0.f);
        *(float4*)(out_end + bi * HH + h0) = acc;
    }
}

extern "C" void kernel_launch(void* const* d_in, const int* in_sizes, int n_in,
                              void* d_out, int out_size, void* d_ws, size_t ws_size,
                              hipStream_t stream) {
    const float* node_feature = (const float*)d_in[0];
    const float* adjacency    = (const float*)d_in[1];
    const float* edge_feature = (const float*)d_in[2];
    // d_in[3] = node_mask (unused by reference math)
    const float* W_edge = (const float*)d_in[4];
    const float* b_edge = (const float*)d_in[5];
    const float* W_feat = (const float*)d_in[6];
    const float* b_feat = (const float*)d_in[7];

    float* out_end  = (float*)d_out;                       // (B,N,H) first
    float* out_edge = out_end + (size_t)BB * NN * HH;      // then (B,N,N,H)

    const size_t pj_bytes = (size_t)BB * NN * HH * sizeof(float);
    if (ws_size >= pj_bytes) {
        float* pj = (float*)d_ws;
        proj_j_kernel<<<(BB * NN * HH + 255) / 256, 256, 0, stream>>>(
            node_feature, W_edge, pj);
        fused_kernel<true><<<BB * NN, 128, 0, stream>>>(
            node_feature, adjacency, edge_feature, W_edge, b_edge,
            W_feat, b_feat, pj, out_end, out_edge);
    } else {
        fused_kernel<false><<<BB * NN, 128, 0, stream>>>(
            node_feature, adjacency, edge_feature, W_edge, b_edge,
            W_feat, b_feat, nullptr, out_end, out_edge);
    }
}

// Round 11
// 138.694 us; speedup vs baseline: 1.0232x; 1.0232x over previous
//
#include <hip/hip_runtime.h>

#define BB 4
#define NN 512
#define DD 16
#define EE 16
#define HH 128

typedef float f32x4 __attribute__((ext_vector_type(4)));

#define LD4(p) (*(const float4*)(p))

// Kernel 1: proj_j[b,j,h] = sum_d node_feature[b,j,d] * W_edge[D+d][h]
__global__ void proj_j_kernel(const float* __restrict__ nf,
                              const float* __restrict__ W_edge,
                              float* __restrict__ pj) {
    int idx = blockIdx.x * 256 + threadIdx.x;
    if (idx >= BB * NN * HH) return;
    int h  = idx & (HH - 1);
    int bj = idx >> 7;
    const float* row = nf + bj * DD;
    float acc = 0.f;
#pragma unroll
    for (int d = 0; d < DD; ++d)
        acc = fmaf(row[d], W_edge[(DD + d) * HH + h], acc);
    pj[idx] = acc;
}

// Kernel 2: one block per (b,i). 128 threads: t&31 -> h-quad, t>>5 -> j-phase.
// UNROLL x4: batch-issue 16 ef + 4 pj loads, compute 4 rows, then fire
// 4 back-to-back NT stores (deep per-wave store queue, memset-like bursts).
template <bool USE_WS>
__global__ __launch_bounds__(128, 2)
void fused_kernel(const float* __restrict__ node_feature,
                  const float* __restrict__ adjacency,
                  const float* __restrict__ edge_feature,
                  const float* __restrict__ W_edge,
                  const float* __restrict__ b_edge,
                  const float* __restrict__ W_feat,
                  const float* __restrict__ b_feat,
                  const float* __restrict__ pj,
                  float* __restrict__ out_end,
                  float* __restrict__ out_edge) {
    const int bi = blockIdx.x;           // b*N + i
    const int b  = bi >> 9;
    const int t  = threadIdx.x;          // 0..127
    const int hq = t & 31;
    const int jl = t >> 5;               // 0..3
    const int h0 = hq * 4;

    // We columns (rows 2D..2D+E-1 of W_edge)
    float4 we[EE];
#pragma unroll
    for (int e = 0; e < EE; ++e)
        we[e] = LD4(W_edge + (2 * DD + e) * HH + h0);

    // pi = b_edge + nf_i @ Wi   (own row i)
    float4 pi = LD4(b_edge + h0);
    {
        const float* nfi = node_feature + bi * DD;
#pragma unroll
        for (int d4 = 0; d4 < DD; d4 += 4) {
            float4 v = LD4(nfi + d4);
            float nd[4] = {v.x, v.y, v.z, v.w};
#pragma unroll
            for (int q = 0; q < 4; ++q) {
                float4 wi = LD4(W_edge + (d4 + q) * HH + h0);
                pi.x = fmaf(nd[q], wi.x, pi.x);
                pi.y = fmaf(nd[q], wi.y, pi.y);
                pi.z = fmaf(nd[q], wi.z, pi.z);
                pi.w = fmaf(nd[q], wi.w, pi.w);
            }
        }
    }

    const float* efb  = edge_feature + (size_t)bi * NN * EE;
    const float* adjr = adjacency + (size_t)bi * NN;
    const float* pjb  = pj + (b * NN) * HH;
    const float* nfb  = node_feature + (b * NN) * DD;
    float*       eob  = out_edge + (size_t)bi * NN * HH;

    float4 msg = make_float4(0.f, 0.f, 0.f, 0.f);

    // 32 outer iterations, each handling 4 rows: j = 16*it + jl + {0,4,8,12}
    for (int it = 0; it < NN / 16; ++it) {
        const int jb = 16 * it + jl;

        // ---- batch-issue ALL loads for 4 rows (deep MLP) ----
        float4 ef[4][4];
        float4 pjv[4];
        float  adjv[4];
#pragma unroll
        for (int r = 0; r < 4; ++r) {
            const int j = jb + 4 * r;
#pragma unroll
            for (int q = 0; q < 4; ++q)
                ef[r][q] = LD4(efb + j * EE + 4 * q);
            if constexpr (USE_WS) pjv[r] = LD4(pjb + j * HH + h0);
            adjv[r] = adjr[j];
        }

        // ---- compute 4 rows into registers ----
        float4 accr[4];
#pragma unroll
        for (int r = 0; r < 4; ++r) {
            float4 acc;
            if constexpr (USE_WS) {
                acc.x = pi.x + pjv[r].x;
                acc.y = pi.y + pjv[r].y;
                acc.z = pi.z + pjv[r].z;
                acc.w = pi.w + pjv[r].w;
            } else {
                acc = pi;
                const float* nfj = nfb + (jb + 4 * r) * DD;
#pragma unroll
                for (int d = 0; d < DD; ++d) {
                    float nv = nfj[d];
                    float4 wj = LD4(W_edge + (DD + d) * HH + h0);
                    acc.x = fmaf(nv, wj.x, acc.x);
                    acc.y = fmaf(nv, wj.y, acc.y);
                    acc.z = fmaf(nv, wj.z, acc.z);
                    acc.w = fmaf(nv, wj.w, acc.w);
                }
            }
#pragma unroll
            for (int q = 0; q < 4; ++q) {
                float ev[4] = {ef[r][q].x, ef[r][q].y, ef[r][q].z, ef[r][q].w};
#pragma unroll
                for (int u = 0; u < 4; ++u) {
                    acc.x = fmaf(ev[u], we[4 * q + u].x, acc.x);
                    acc.y = fmaf(ev[u], we[4 * q + u].y, acc.y);
                    acc.z = fmaf(ev[u], we[4 * q + u].z, acc.z);
                    acc.w = fmaf(ev[u], we[4 * q + u].w, acc.w);
                }
            }
            acc.x = fmaxf(acc.x, 0.f);
            acc.y = fmaxf(acc.y, 0.f);
            acc.z = fmaxf(acc.z, 0.f);
            acc.w = fmaxf(acc.w, 0.f);
            accr[r] = acc;

            msg.x = fmaf(adjv[r], acc.x, msg.x);
            msg.y = fmaf(adjv[r], acc.y, msg.y);
            msg.z = fmaf(adjv[r], acc.z, msg.z);
            msg.w = fmaf(adjv[r], acc.w, msg.w);
        }

        // ---- burst: 4 back-to-back NT stores ----
#pragma unroll
        for (int r = 0; r < 4; ++r) {
            __builtin_nontemporal_store(
                (f32x4){accr[r].x, accr[r].y, accr[r].z, accr[r].w},
                (f32x4*)(eob + (size_t)(jb + 4 * r) * HH + h0));
        }
    }

    // Reduce message across the 4 j-phases, then ending = relu([msg,nf]@W_feat + b_feat)
    __shared__ float msgred[4][HH];
    *(float4*)&msgred[jl][h0] = msg;
    __syncthreads();

    if (jl == 0) {
        float4 acc = LD4(b_feat + h0);
#pragma unroll 4
        for (int k = 0; k < HH; ++k) {
            float m = msgred[0][k] + msgred[1][k] + msgred[2][k] + msgred[3][k];
            float4 w = LD4(W_feat + k * HH + h0);
            acc.x = fmaf(m, w.x, acc.x);
            acc.y = fmaf(m, w.y, acc.y);
            acc.z = fmaf(m, w.z, acc.z);
            acc.w = fmaf(m, w.w, acc.w);
        }
        const float* nfi = node_feature + bi * DD;
#pragma unroll
        for (int d = 0; d < DD; ++d) {
            float m = nfi[d];
            float4 w = LD4(W_feat + (HH + d) * HH + h0);
            acc.x = fmaf(m, w.x, acc.x);
            acc.y = fmaf(m, w.y, acc.y);
            acc.z = fmaf(m, w.z, acc.z);
            acc.w = fmaf(m, w.w, acc.w);
        }
        acc.x = fmaxf(acc.x, 0.f);
        acc.y = fmaxf(acc.y, 0.f);
        acc.z = fmaxf(acc.z, 0.f);
        acc.w = fmaxf(acc.w, 0.f);
        *(float4*)(out_end + bi * HH + h0) = acc;
    }
}

extern "C" void kernel_launch(void* const* d_in, const int* in_sizes, int n_in,
                              void* d_out, int out_size, void* d_ws, size_t ws_size,
                              hipStream_t stream) {
    const float* node_feature = (const float*)d_in[0];
    const float* adjacency    = (const float*)d_in[1];
    const float* edge_feature = (const float*)d_in[2];
    // d_in[3] = node_mask (unused by reference math)
    const float* W_edge = (const float*)d_in[4];
    const float* b_edge = (const float*)d_in[5];
    const float* W_feat = (const float*)d_in[6];
    const float* b_feat = (const float*)d_in[7];

    float* out_end  = (float*)d_out;                       // (B,N,H) first
    float* out_edge = out_end + (size_t)BB * NN * HH;      // then (B,N,N,H)

    const size_t pj_bytes = (size_t)BB * NN * HH * sizeof(float);
    if (ws_size >= pj_bytes) {
        float* pj = (float*)d_ws;
        proj_j_kernel<<<(BB * NN * HH + 255) / 256, 256, 0, stream>>>(
            node_feature, W_edge, pj);
        fused_kernel<true><<<BB * NN, 128, 0, stream>>>(
            node_feature, adjacency, edge_feature, W_edge, b_edge,
            W_feat, b_feat, pj, out_end, out_edge);
    } else {
        fused_kernel<false><<<BB * NN, 128, 0, stream>>>(
            node_feature, adjacency, edge_feature, W_edge, b_edge,
            W_feat, b_feat, nullptr, out_end, out_edge);
    }
}

// Round 12
// 135.862 us; speedup vs baseline: 1.0446x; 1.0208x over previous
//
#include <hip/hip_runtime.h>

#define BB 4
#define NN 512
#define DD 16
#define EE 16
#define HH 128
#define NXCD 8

typedef float f32x4 __attribute__((ext_vector_type(4)));

#define LD4(p) (*(const float4*)(p))

// Kernel 1: proj_j[b,j,h] = sum_d node_feature[b,j,d] * W_edge[D+d][h]
__global__ void proj_j_kernel(const float* __restrict__ nf,
                              const float* __restrict__ W_edge,
                              float* __restrict__ pj) {
    int idx = blockIdx.x * 256 + threadIdx.x;
    if (idx >= BB * NN * HH) return;
    int h  = idx & (HH - 1);
    int bj = idx >> 7;
    const float* row = nf + bj * DD;
    float acc = 0.f;
#pragma unroll
    for (int d = 0; d < DD; ++d)
        acc = fmaf(row[d], W_edge[(DD + d) * HH + h], acc);
    pj[idx] = acc;
}

// Kernel 2: one block per (b,i), XCD-swizzled so each XCD owns a CONTIGUOUS
// 64MB slice of out_edge (better dirty-evict / DRAM page locality per MC).
// 128 threads: t&31 -> h-quad, t>>5 -> j-phase. x4-unrolled burst NT stores.
template <bool USE_WS>
__global__ __launch_bounds__(128, 2)
void fused_kernel(const float* __restrict__ node_feature,
                  const float* __restrict__ adjacency,
                  const float* __restrict__ edge_feature,
                  const float* __restrict__ W_edge,
                  const float* __restrict__ b_edge,
                  const float* __restrict__ W_feat,
                  const float* __restrict__ b_feat,
                  const float* __restrict__ pj,
                  float* __restrict__ out_end,
                  float* __restrict__ out_edge) {
    // XCD-aware bijective swizzle: hw block g runs on XCD g%8 (round-robin
    // dispatch); give XCD k the contiguous bi range [k*256, (k+1)*256).
    const int g  = blockIdx.x;
    const int bi = (g % NXCD) * (BB * NN / NXCD) + (g / NXCD);
    const int b  = bi >> 9;
    const int t  = threadIdx.x;          // 0..127
    const int hq = t & 31;
    const int jl = t >> 5;               // 0..3
    const int h0 = hq * 4;

    // We columns (rows 2D..2D+E-1 of W_edge)
    float4 we[EE];
#pragma unroll
    for (int e = 0; e < EE; ++e)
        we[e] = LD4(W_edge + (2 * DD + e) * HH + h0);

    // pi = b_edge + nf_i @ Wi   (own row i)
    float4 pi = LD4(b_edge + h0);
    {
        const float* nfi = node_feature + bi * DD;
#pragma unroll
        for (int d4 = 0; d4 < DD; d4 += 4) {
            float4 v = LD4(nfi + d4);
            float nd[4] = {v.x, v.y, v.z, v.w};
#pragma unroll
            for (int q = 0; q < 4; ++q) {
                float4 wi = LD4(W_edge + (d4 + q) * HH + h0);
                pi.x = fmaf(nd[q], wi.x, pi.x);
                pi.y = fmaf(nd[q], wi.y, pi.y);
                pi.z = fmaf(nd[q], wi.z, pi.z);
                pi.w = fmaf(nd[q], wi.w, pi.w);
            }
        }
    }

    const float* efb  = edge_feature + (size_t)bi * NN * EE;
    const float* adjr = adjacency + (size_t)bi * NN;
    const float* pjb  = pj + (b * NN) * HH;
    const float* nfb  = node_feature + (b * NN) * DD;
    float*       eob  = out_edge + (size_t)bi * NN * HH;

    float4 msg = make_float4(0.f, 0.f, 0.f, 0.f);

    // 32 outer iterations, each handling 4 rows: j = 16*it + jl + {0,4,8,12}
    for (int it = 0; it < NN / 16; ++it) {
        const int jb = 16 * it + jl;

        // ---- batch-issue ALL loads for 4 rows (deep MLP) ----
        float4 ef[4][4];
        float4 pjv[4];
        float  adjv[4];
#pragma unroll
        for (int r = 0; r < 4; ++r) {
            const int j = jb + 4 * r;
#pragma unroll
            for (int q = 0; q < 4; ++q)
                ef[r][q] = LD4(efb + j * EE + 4 * q);
            if constexpr (USE_WS) pjv[r] = LD4(pjb + j * HH + h0);
            adjv[r] = adjr[j];
        }

        // ---- compute 4 rows into registers ----
        float4 accr[4];
#pragma unroll
        for (int r = 0; r < 4; ++r) {
            float4 acc;
            if constexpr (USE_WS) {
                acc.x = pi.x + pjv[r].x;
                acc.y = pi.y + pjv[r].y;
                acc.z = pi.z + pjv[r].z;
                acc.w = pi.w + pjv[r].w;
            } else {
                acc = pi;
                const float* nfj = nfb + (jb + 4 * r) * DD;
#pragma unroll
                for (int d = 0; d < DD; ++d) {
                    float nv = nfj[d];
                    float4 wj = LD4(W_edge + (DD + d) * HH + h0);
                    acc.x = fmaf(nv, wj.x, acc.x);
                    acc.y = fmaf(nv, wj.y, acc.y);
                    acc.z = fmaf(nv, wj.z, acc.z);
                    acc.w = fmaf(nv, wj.w, acc.w);
                }
            }
#pragma unroll
            for (int q = 0; q < 4; ++q) {
                float ev[4] = {ef[r][q].x, ef[r][q].y, ef[r][q].z, ef[r][q].w};
#pragma unroll
                for (int u = 0; u < 4; ++u) {
                    acc.x = fmaf(ev[u], we[4 * q + u].x, acc.x);
                    acc.y = fmaf(ev[u], we[4 * q + u].y, acc.y);
                    acc.z = fmaf(ev[u], we[4 * q + u].z, acc.z);
                    acc.w = fmaf(ev[u], we[4 * q + u].w, acc.w);
                }
            }
            acc.x = fmaxf(acc.x, 0.f);
            acc.y = fmaxf(acc.y, 0.f);
            acc.z = fmaxf(acc.z, 0.f);
            acc.w = fmaxf(acc.w, 0.f);
            accr[r] = acc;

            msg.x = fmaf(adjv[r], acc.x, msg.x);
            msg.y = fmaf(adjv[r], acc.y, msg.y);
            msg.z = fmaf(adjv[r], acc.z, msg.z);
            msg.w = fmaf(adjv[r], acc.w, msg.w);
        }

        // ---- burst: 4 back-to-back NT stores ----
#pragma unroll
        for (int r = 0; r < 4; ++r) {
            __builtin_nontemporal_store(
                (f32x4){accr[r].x, accr[r].y, accr[r].z, accr[r].w},
                (f32x4*)(eob + (size_t)(jb + 4 * r) * HH + h0));
        }
    }

    // Reduce message across the 4 j-phases, then ending = relu([msg,nf]@W_feat + b_feat)
    __shared__ float msgred[4][HH];
    *(float4*)&msgred[jl][h0] = msg;
    __syncthreads();

    if (jl == 0) {
        float4 acc = LD4(b_feat + h0);
#pragma unroll 4
        for (int k = 0; k < HH; ++k) {
            float m = msgred[0][k] + msgred[1][k] + msgred[2][k] + msgred[3][k];
            float4 w = LD4(W_feat + k * HH + h0);
            acc.x = fmaf(m, w.x, acc.x);
            acc.y = fmaf(m, w.y, acc.y);
            acc.z = fmaf(m, w.z, acc.z);
            acc.w = fmaf(m, w.w, acc.w);
        }
        const float* nfi = node_feature + bi * DD;
#pragma unroll
        for (int d = 0; d < DD; ++d) {
            float m = nfi[d];
            float4 w = LD4(W_feat + (HH + d) * HH + h0);
            acc.x = fmaf(m, w.x, acc.x);
            acc.y = fmaf(m, w.y, acc.y);
            acc.z = fmaf(m, w.z, acc.z);
            acc.w = fmaf(m, w.w, acc.w);
        }
        acc.x = fmaxf(acc.x, 0.f);
        acc.y = fmaxf(acc.y, 0.f);
        acc.z = fmaxf(acc.z, 0.f);
        acc.w = fmaxf(acc.w, 0.f);
        *(float4*)(out_end + bi * HH + h0) = acc;
    }
}

extern "C" void kernel_launch(void* const* d_in, const int* in_sizes, int n_in,
                              void* d_out, int out_size, void* d_ws, size_t ws_size,
                              hipStream_t stream) {
    const float* node_feature = (const float*)d_in[0];
    const float* adjacency    = (const float*)d_in[1];
    const float* edge_feature = (const float*)d_in[2];
    // d_in[3] = node_mask (unused by reference math)
    const float* W_edge = (const float*)d_in[4];
    const float* b_edge = (const float*)d_in[5];
    const float* W_feat = (const float*)d_in[6];
    const float* b_feat = (const float*)d_in[7];

    float* out_end  = (float*)d_out;                       // (B,N,H) first
    float* out_edge = out_end + (size_t)BB * NN * HH;      // then (B,N,N,H)

    const size_t pj_bytes = (size_t)BB * NN * HH * sizeof(float);
    if (ws_size >= pj_bytes) {
        float* pj = (float*)d_ws;
        proj_j_kernel<<<(BB * NN * HH + 255) / 256, 256, 0, stream>>>(
            node_feature, W_edge, pj);
        fused_kernel<true><<<BB * NN, 128, 0, stream>>>(
            node_feature, adjacency, edge_feature, W_edge, b_edge,
            W_feat, b_feat, pj, out_end, out_edge);
    } else {
        fused_kernel<false><<<BB * NN, 128, 0, stream>>>(
            node_feature, adjacency, edge_feature, W_edge, b_edge,
            W_feat, b_feat, nullptr, out_end, out_edge);
    }
}